// Round 7
// baseline (506.116 us; speedup 1.0000x reference)
//
#include <hip/hip_runtime.h>
#include <hip/hip_bf16.h>
#include <math.h>

#define S_LEN 1024
#define HIDN  1024
#define NHEAD 16
#define HDIM  64
#define BATCH 4
#define MTOT  (BATCH * S_LEN)   // 4096

typedef __attribute__((ext_vector_type(8))) short          bf16v8;
typedef __attribute__((ext_vector_type(8))) unsigned short u16v8;
typedef __attribute__((ext_vector_type(4))) unsigned short u16v4;
typedef __attribute__((ext_vector_type(4))) float          f32v4;

// ---------------------------------------------------------------------------
// bf16 hi/lo split helpers (RNE)
// ---------------------------------------------------------------------------
__device__ __forceinline__ unsigned short f2bf_rne(float x) {
    unsigned int u = __float_as_uint(x);
    unsigned int r = (u + 0x7fffu + ((u >> 16) & 1u)) >> 16;
    return (unsigned short)r;
}
__device__ __forceinline__ float bf2f(unsigned short h) {
    return __uint_as_float(((unsigned int)h) << 16);
}
__device__ __forceinline__ void split2(float x, unsigned short& h, unsigned short& l) {
    h = f2bf_rne(x);
    l = f2bf_rne(x - bf2f(h));
}

// ---------------------------------------------------------------------------
// split_a: row-major f32 [M][1024] -> Ah, Al bf16 (same layout).
// ---------------------------------------------------------------------------
__global__ __launch_bounds__(256) void split_a(
    const float* __restrict__ X, unsigned short* __restrict__ H,
    unsigned short* __restrict__ L)
{
    const int i = blockIdx.x * 256 + threadIdx.x;
    const float4 x0 = ((const float4*)X)[2 * i];
    const float4 x1 = ((const float4*)X)[2 * i + 1];
    float xs[8] = {x0.x, x0.y, x0.z, x0.w, x1.x, x1.y, x1.z, x1.w};
    u16v8 h, l;
#pragma unroll
    for (int j = 0; j < 8; ++j) {
        unsigned short hh, ll;
        split2(xs[j], hh, ll);
        h[j] = hh; l[j] = ll;
    }
    ((u16v8*)H)[i] = h;
    ((u16v8*)L)[i] = l;
}

// ---------------------------------------------------------------------------
// split_w: W f32 [K=1024][N=1024] -> transposed Ht, Lt bf16 [N][K] (k-contig).
// ---------------------------------------------------------------------------
__global__ __launch_bounds__(256) void split_w(
    const float* __restrict__ W, unsigned short* __restrict__ H,
    unsigned short* __restrict__ L)
{
    __shared__ float T[64][65];
    const int t  = threadIdx.x;
    const int k0 = blockIdx.y * 64;
    const int n0 = blockIdx.x * 64;

    const int r = t >> 4;
    const int c = (t & 15) * 4;
#pragma unroll
    for (int i = 0; i < 4; ++i) {
        const int rr = r + i * 16;
        const float4 v = *(const float4*)&W[(size_t)(k0 + rr) * 1024 + n0 + c];
        T[rr][c + 0] = v.x; T[rr][c + 1] = v.y;
        T[rr][c + 2] = v.z; T[rr][c + 3] = v.w;
    }
    __syncthreads();

    const int n  = t >> 2;
    const int ko = (t & 3) * 16;
    u16v8 h0, h1, l0, l1;
#pragma unroll
    for (int kk = 0; kk < 8; ++kk) {
        unsigned short hh, ll;
        split2(T[ko + kk][n], hh, ll);
        h0[kk] = hh; l0[kk] = ll;
    }
#pragma unroll
    for (int kk = 0; kk < 8; ++kk) {
        unsigned short hh, ll;
        split2(T[ko + 8 + kk][n], hh, ll);
        h1[kk] = hh; l1[kk] = ll;
    }
    unsigned short* Hp = &H[(size_t)(n0 + n) * 1024 + k0 + ko];
    unsigned short* Lp = &L[(size_t)(n0 + n) * 1024 + k0 + ko];
    *(u16v8*)(Hp)     = h0;
    *(u16v8*)(Hp + 8) = h1;
    *(u16v8*)(Lp)     = l0;
    *(u16v8*)(Lp + 8) = l1;
}

// ---------------------------------------------------------------------------
// bf16x3 MFMA GEMM: C = A(hi/lo bf16 [M][1024]) @ B(hi/lo [n][k]) + bias.
// BM=128, BN=64, BK=32, 512 threads (8 waves 4x2), wave 32x32 out.
// Grid (16,32)=512 blocks -> 2 blocks/CU x 8 waves = 16 waves/CU (50%).
// ---------------------------------------------------------------------------
__global__ __launch_bounds__(512, 4) void gemm_bf16x3(
    const unsigned short* __restrict__ Ah, const unsigned short* __restrict__ Al,
    const unsigned short* __restrict__ Bh, const unsigned short* __restrict__ Bl,
    const float* __restrict__ bias, float* __restrict__ Cf,
    unsigned short* __restrict__ Ch, unsigned short* __restrict__ Cl, int vt)
{
    __shared__ short Ash[128][40];
    __shared__ short Asl[128][40];
    __shared__ short Bsh[64][40];
    __shared__ short Bsl[64][40];

    const int t    = threadIdx.x;
    const int bm   = blockIdx.y * 128;
    const int bn   = blockIdx.x * 64;
    const int lane = t & 63;
    const int wid  = t >> 6;        // 0..7
    const int wr   = wid >> 1;      // 0..3 -> rows wr*32
    const int wc   = wid & 1;       // cols wc*32
    const int fr   = lane & 15;
    const int fq   = lane >> 4;
    const int ks   = fq * 8;

    f32v4 zero = {0.f, 0.f, 0.f, 0.f};
    f32v4 acc[2][2];
#pragma unroll
    for (int i = 0; i < 2; ++i)
#pragma unroll
        for (int j = 0; j < 2; ++j) acc[i][j] = zero;

    // staging roles: each thread 1 chunk of Ah + Al; half threads Bh, half Bl
    const int sra = t >> 2;          // 0..127
    const int sca = (t & 3) * 8;
    const int tb  = t & 255;
    const int srb = tb >> 2;         // 0..63
    const int scb = (tb & 3) * 8;
    const bool isBl = (t >= 256);
    const unsigned short* pAh = &Ah[(size_t)(bm + sra) * 1024 + sca];
    const unsigned short* pAl = &Al[(size_t)(bm + sra) * 1024 + sca];
    const unsigned short* pB  = isBl ? &Bl[(size_t)(bn + srb) * 1024 + scb]
                                     : &Bh[(size_t)(bn + srb) * 1024 + scb];

    u16v8 rah, ral, rb;
    auto LOAD = [&](int k0) {
        rah = *(const u16v8*)(pAh + k0);
        ral = *(const u16v8*)(pAl + k0);
        rb  = *(const u16v8*)(pB  + k0);
    };

    LOAD(0);
    for (int k0 = 0; k0 < 1024; k0 += 32) {
        __syncthreads();
        *(u16v8*)&Ash[sra][sca] = rah;
        *(u16v8*)&Asl[sra][sca] = ral;
        if (isBl) *(u16v8*)&Bsl[srb][scb] = rb;
        else      *(u16v8*)&Bsh[srb][scb] = rb;
        __syncthreads();

        if (k0 + 32 < 1024) LOAD(k0 + 32);

        bf16v8 fah[2], fal[2], fbh[2], fbl[2];
#pragma unroll
        for (int i = 0; i < 2; ++i) {
            fah[i] = *(const bf16v8*)&Ash[wr * 32 + i * 16 + fr][ks];
            fal[i] = *(const bf16v8*)&Asl[wr * 32 + i * 16 + fr][ks];
        }
#pragma unroll
        for (int j = 0; j < 2; ++j) {
            fbh[j] = *(const bf16v8*)&Bsh[wc * 32 + j * 16 + fr][ks];
            fbl[j] = *(const bf16v8*)&Bsl[wc * 32 + j * 16 + fr][ks];
        }
#pragma unroll
        for (int i = 0; i < 2; ++i)
#pragma unroll
            for (int j = 0; j < 2; ++j) {
                acc[i][j] = __builtin_amdgcn_mfma_f32_16x16x32_bf16(
                    fah[i], fbh[j], acc[i][j], 0, 0, 0);
                acc[i][j] = __builtin_amdgcn_mfma_f32_16x16x32_bf16(
                    fah[i], fbl[j], acc[i][j], 0, 0, 0);
                acc[i][j] = __builtin_amdgcn_mfma_f32_16x16x32_bf16(
                    fal[i], fbh[j], acc[i][j], 0, 0, 0);
            }
    }

#pragma unroll
    for (int j = 0; j < 2; ++j) {
        const int col = bn + wc * 32 + j * 16 + fr;
        const float bb = bias[col];
#pragma unroll
        for (int i = 0; i < 2; ++i) {
            const int row0 = bm + wr * 32 + i * 16 + fq * 4;
            const f32v4 cv = acc[i][j];
            if (vt) {
                u16v4 h4, l4;
#pragma unroll
                for (int r = 0; r < 4; ++r) {
                    unsigned short hh, ll;
                    split2(cv[r] + bb, hh, ll);
                    h4[r] = hh; l4[r] = ll;
                }
                const size_t base =
                    ((size_t)((row0 >> 10) * 16 + (col >> 6)) * 64 + (col & 63)) * 1024
                    + (row0 & 1023);
                *(u16v4*)&Ch[base] = h4;
                *(u16v4*)&Cl[base] = l4;
            } else {
#pragma unroll
                for (int r = 0; r < 4; ++r) {
                    const float v = cv[r] + bb;
                    const size_t idx = (size_t)(row0 + r) * 1024 + col;
                    if (Cf) Cf[idx] = v;
                    if (Ch) {
                        unsigned short hh, ll;
                        split2(v, hh, ll);
                        Ch[idx] = hh; Cl[idx] = ll;
                    }
                }
            }
        }
    }
}

// ---------------------------------------------------------------------------
// alpha = sigmoid(query @ Wus + bus)   [MTOT,16]
// ---------------------------------------------------------------------------
__global__ __launch_bounds__(256) void alpha_kernel(
    const float* __restrict__ X, const float* __restrict__ Wus,
    const float* __restrict__ bus, float* __restrict__ alpha)
{
    __shared__ float Ws[1024 * 16];
    const int t = threadIdx.x;
#pragma unroll
    for (int i = 0; i < 16; ++i) {
        const int idx = t + i * 256;
        *reinterpret_cast<float4*>(&Ws[idx * 4]) =
            *reinterpret_cast<const float4*>(&Wus[idx * 4]);
    }
    __syncthreads();

    const int r = t >> 4, c = t & 15;
    const size_t row = (size_t)blockIdx.x * 16 + r;
    const float* x = &X[row * 1024];
    float acc = 0.f;
    for (int kk = 0; kk < 1024; kk += 4) {
        const float4 xv = *reinterpret_cast<const float4*>(&x[kk]);
        acc = fmaf(xv.x, Ws[(kk + 0) * 16 + c], acc);
        acc = fmaf(xv.y, Ws[(kk + 1) * 16 + c], acc);
        acc = fmaf(xv.z, Ws[(kk + 2) * 16 + c], acc);
        acc = fmaf(xv.w, Ws[(kk + 3) * 16 + c], acc);
    }
    acc += bus[c];
    alpha[row * 16 + c] = 1.f / (1.f + expf(-acc));
}

// ---------------------------------------------------------------------------
// Gaussian-window parameters per (b,h,s)
// ---------------------------------------------------------------------------
__global__ __launch_bounds__(256) void posparam_kernel(
    const float* __restrict__ p, const float* __restrict__ alpha,
    const float* __restrict__ Wup, const float* __restrict__ bup,
    const float* __restrict__ Wud, const float* __restrict__ bud,
    float* __restrict__ cen, float* __restrict__ c0)
{
    __shared__ float wu[64], wd[64];
    const int t = threadIdx.x;
    if (t < 64) { wu[t] = Wup[t]; wd[t] = Wud[t]; }
    __syncthreads();

    const int tid = blockIdx.x * 256 + t;
    const int b = tid >> 14;
    const int h = (tid >> 10) & 15;
    const int s = tid & 1023;

    const float* pr = &p[((size_t)(b * 1024 + s)) * 1024 + h * 64];
    float ap = 0.f, az = 0.f;
#pragma unroll
    for (int d = 0; d < 64; d += 4) {
        const float4 pv = *reinterpret_cast<const float4*>(&pr[d]);
        const float t0 = tanhf(pv.x), t1 = tanhf(pv.y);
        const float t2 = tanhf(pv.z), t3 = tanhf(pv.w);
        ap += t0 * wu[d] + t1 * wu[d + 1] + t2 * wu[d + 2] + t3 * wu[d + 3];
        az += t0 * wd[d] + t1 * wd[d + 1] + t2 * wd[d + 2] + t3 * wd[d + 3];
    }
    ap += bup[0];
    az += bud[0];
    const float cenv = 1024.f / (1.f + expf(-ap));
    const float win  = 1024.f / (1.f + expf(-az));
    const float al   = alpha[(size_t)(b * 1024 + s) * 16 + h];
    const int oi = (b * 16 + h) * 1024 + s;
    cen[oi] = cenv;
    c0[oi]  = al * 2.f / (win * win);
}

// ---------------------------------------------------------------------------
// attn_fused v4: r4 geometry (i-tile 128, grid 512, same swizzles) with
// 512 threads (8 waves: 4 row-groups x 2 col-groups, wave 32q x 32j) and
// register prefetch of next j-tile's K/V (latency hides under MFMA/exp).
// 2 blocks/CU x 8 waves = 16 waves/CU (50% occupancy cap).
// ---------------------------------------------------------------------------
#define M0_SHIFT 8.0f
__global__ __launch_bounds__(512, 4) void attn_fused(
    const unsigned short* __restrict__ qh, const unsigned short* __restrict__ ql,
    const unsigned short* __restrict__ kh, const unsigned short* __restrict__ kl,
    const unsigned short* __restrict__ vTh, const unsigned short* __restrict__ vTl,
    const float* __restrict__ cen, const float* __restrict__ c0,
    float* __restrict__ attn,
    unsigned short* __restrict__ oh, unsigned short* __restrict__ ol)
{
    __shared__ unsigned short KH[64][64], KL[64][64];   // 16 KB
    __shared__ unsigned short VH[64][64], VL[64][64];   // 16 KB
    __shared__ unsigned short PH[128][64], PL[128][64]; // 32 KB
    __shared__ float CEN[128], C0S[128];
    __shared__ float LSUM[2][128];
    __shared__ float RINV[128];

    // XCD mapping: all 8 i-tiles of one z land on one XCD (bid&7 = XCD)
    const int bid   = blockIdx.x;
    const int z     = ((bid >> 6) << 3) | (bid & 7);
    const int itile = (bid >> 3) & 7;
    const int i0    = itile * 128;
    const int bq    = z >> 4;
    const int hd    = z & 15;

    const int t    = threadIdx.x;
    const int lane = t & 63;
    const int wid  = t >> 6;        // 0..7
    const int wrp  = wid >> 1;      // 0..3 -> q rows wrp*32
    const int wc   = wid & 1;       // j cols wc*32
    const int fr   = lane & 15, fq = lane >> 4;

    if (t < 128) {
        CEN[t] = cen[(size_t)z * 1024 + i0 + t];
        C0S[t] = c0[(size_t)z * 1024 + i0 + t];
    }

    // Q fragments in registers (A-frag: row = fr, k = kk*32 + fq*8)
    bf16v8 qfh_[2][2], qfl_[2][2];
#pragma unroll
    for (int i = 0; i < 2; ++i)
#pragma unroll
        for (int kk = 0; kk < 2; ++kk) {
            const size_t qa = (size_t)(bq * 1024 + i0 + wrp * 32 + i * 16 + fr) * 1024
                              + hd * 64 + kk * 32 + fq * 8;
            qfh_[i][kk] = *(const bf16v8*)&qh[qa];
            qfl_[i][kk] = *(const bf16v8*)&ql[qa];
        }

    float lsum[2][4];
#pragma unroll
    for (int i = 0; i < 2; ++i)
#pragma unroll
        for (int r = 0; r < 4; ++r) lsum[i][r] = 0.f;

    const f32v4 zero = {0.f, 0.f, 0.f, 0.f};

    // staging role: thread -> K/V row (t>>3, 0..63), 8-elem seg (t&7)
    const int srow = t >> 3;
    const int sseg = t & 7;
    const int ssl  = (sseg ^ (srow & 7)) * 8;
    const unsigned short* vhb = vTh + (size_t)z * 64 * 1024;
    const unsigned short* vlb = vTl + (size_t)z * 64 * 1024;

    u16v8 rkh, rkl, rvh, rvl;
    auto LOADK = [&](int j0) {
        const size_t ga = (size_t)(bq * 1024 + j0 + srow) * 1024 + hd * 64 + sseg * 8;
        rkh = *(const u16v8*)&kh[ga];
        rkl = *(const u16v8*)&kl[ga];
    };
    auto LOADV = [&](int j0) {
        const size_t va = (size_t)srow * 1024 + j0 + sseg * 8;
        rvh = *(const u16v8*)&vhb[va];
        rvl = *(const u16v8*)&vlb[va];
    };

    // ---------------- PASS A: row sums ----------------
    LOADK(0);
    for (int jt = 0; jt < 16; ++jt) {
        const int j0 = jt * 64;
        __syncthreads();            // prev tile's readers done (also CEN ready)
        *(u16v8*)&KH[srow][ssl] = rkh;
        *(u16v8*)&KL[srow][ssl] = rkl;
        __syncthreads();
        if (jt < 15) LOADK(j0 + 64);   // prefetch next tile under compute

        f32v4 acc[2][2];
#pragma unroll
        for (int i = 0; i < 2; ++i)
#pragma unroll
            for (int j2 = 0; j2 < 2; ++j2) acc[i][j2] = zero;

#pragma unroll
        for (int kk = 0; kk < 2; ++kk) {
            bf16v8 fbh[2], fbl[2];
#pragma unroll
            for (int j2 = 0; j2 < 2; ++j2) {
                const int rb = wc * 32 + j2 * 16 + fr;
                const int sb = ((kk * 4 + fq) ^ (rb & 7)) * 8;
                fbh[j2] = *(const bf16v8*)&KH[rb][sb];
                fbl[j2] = *(const bf16v8*)&KL[rb][sb];
            }
#pragma unroll
            for (int i = 0; i < 2; ++i)
#pragma unroll
                for (int j2 = 0; j2 < 2; ++j2) {
                    acc[i][j2] = __builtin_amdgcn_mfma_f32_16x16x32_bf16(
                        qfh_[i][kk], fbh[j2], acc[i][j2], 0, 0, 0);
                    acc[i][j2] = __builtin_amdgcn_mfma_f32_16x16x32_bf16(
                        qfh_[i][kk], fbl[j2], acc[i][j2], 0, 0, 0);
                    acc[i][j2] = __builtin_amdgcn_mfma_f32_16x16x32_bf16(
                        qfl_[i][kk], fbh[j2], acc[i][j2], 0, 0, 0);
                }
        }

#pragma unroll
        for (int i = 0; i < 2; ++i)
#pragma unroll
            for (int r = 0; r < 4; ++r) {
                const int row = wrp * 32 + i * 16 + fq * 4 + r;
                const float cv = CEN[row], cc = C0S[row];
                float al = 0.f;
#pragma unroll
                for (int j2 = 0; j2 < 2; ++j2) {
                    const int col = wc * 32 + j2 * 16 + fr;
                    const float dd = (float)(j0 + col) - cv;
                    const float s  = acc[i][j2][r] * 0.125f - cc * dd * dd;
                    al += __expf(s - M0_SHIFT);
                }
                lsum[i][r] += al;
            }
    }

    // reduce over fr lanes, combine wc halves via LDS
#pragma unroll
    for (int i = 0; i < 2; ++i)
#pragma unroll
        for (int r = 0; r < 4; ++r) {
            float v = lsum[i][r];
            v += __shfl_xor(v, 1);
            v += __shfl_xor(v, 2);
            v += __shfl_xor(v, 4);
            v += __shfl_xor(v, 8);
            if (fr == 0) LSUM[wc][wrp * 32 + i * 16 + fq * 4 + r] = v;
        }
    __syncthreads();
    if (t < 128) RINV[t] = 1.f / (LSUM[0][t] + LSUM[1][t]);

    // ---------------- PASS B: attn write + PV ----------------
    f32v4 acco[2][2];
#pragma unroll
    for (int i = 0; i < 2; ++i)
#pragma unroll
        for (int j = 0; j < 2; ++j) acco[i][j] = zero;

    float* attnZ = attn + (size_t)z * 1024 * 1024;

    LOADK(0);
    LOADV(0);
    for (int jt = 0; jt < 16; ++jt) {
        const int j0 = jt * 64;
        __syncthreads();   // prev PV reads done; RINV visible on first iter
        *(u16v8*)&KH[srow][ssl] = rkh;
        *(u16v8*)&KL[srow][ssl] = rkl;
        *(u16v8*)&VH[srow][ssl] = rvh;
        *(u16v8*)&VL[srow][ssl] = rvl;
        __syncthreads();
        if (jt < 15) { LOADK(j0 + 64); LOADV(j0 + 64); }

        f32v4 acc[2][2];
#pragma unroll
        for (int i = 0; i < 2; ++i)
#pragma unroll
            for (int j2 = 0; j2 < 2; ++j2) acc[i][j2] = zero;

#pragma unroll
        for (int kk = 0; kk < 2; ++kk) {
            bf16v8 fbh[2], fbl[2];
#pragma unroll
            for (int j2 = 0; j2 < 2; ++j2) {
                const int rb = wc * 32 + j2 * 16 + fr;
                const int sb = ((kk * 4 + fq) ^ (rb & 7)) * 8;
                fbh[j2] = *(const bf16v8*)&KH[rb][sb];
                fbl[j2] = *(const bf16v8*)&KL[rb][sb];
            }
#pragma unroll
            for (int i = 0; i < 2; ++i)
#pragma unroll
                for (int j2 = 0; j2 < 2; ++j2) {
                    acc[i][j2] = __builtin_amdgcn_mfma_f32_16x16x32_bf16(
                        qfh_[i][kk], fbh[j2], acc[i][j2], 0, 0, 0);
                    acc[i][j2] = __builtin_amdgcn_mfma_f32_16x16x32_bf16(
                        qfh_[i][kk], fbl[j2], acc[i][j2], 0, 0, 0);
                    acc[i][j2] = __builtin_amdgcn_mfma_f32_16x16x32_bf16(
                        qfl_[i][kk], fbh[j2], acc[i][j2], 0, 0, 0);
                }
        }

        // P = exp(s-8)*rinv: write attn f32 + scatter bf16 hi/lo to LDS
#pragma unroll
        for (int i = 0; i < 2; ++i)
#pragma unroll
            for (int r = 0; r < 4; ++r) {
                const int row = wrp * 32 + i * 16 + fq * 4 + r;
                const float cv = CEN[row], cc = C0S[row], ri = RINV[row];
#pragma unroll
                for (int j2 = 0; j2 < 2; ++j2) {
                    const int col = wc * 32 + j2 * 16 + fr;
                    const float dd = (float)(j0 + col) - cv;
                    const float s  = acc[i][j2][r] * 0.125f - cc * dd * dd;
                    const float p  = __expf(s - M0_SHIFT) * ri;
                    attnZ[(size_t)(i0 + row) * 1024 + j0 + col] = p;
                    unsigned short hv, lv;
                    split2(p, hv, lv);
                    const int slot = ((col >> 3) ^ (row & 7)) * 8 + (col & 7);
                    PH[row][slot] = hv;
                    PL[row][slot] = lv;
                }
            }
        __syncthreads();

        // PV MFMA: out[128 q][64 d] += P[128][64] @ Vt[64 d][64 j]^T
#pragma unroll
        for (int kk = 0; kk < 2; ++kk) {
            bf16v8 pah[2], pal[2], fbh[2], fbl[2];
#pragma unroll
            for (int iq = 0; iq < 2; ++iq) {
                const int rp = wrp * 32 + iq * 16 + fr;
                const int sp = ((kk * 4 + fq) ^ (rp & 7)) * 8;
                pah[iq] = *(const bf16v8*)&PH[rp][sp];
                pal[iq] = *(const bf16v8*)&PL[rp][sp];
            }
#pragma unroll
            for (int jd = 0; jd < 2; ++jd) {
                const int rb = wc * 32 + jd * 16 + fr;
                const int sb = ((kk * 4 + fq) ^ (rb & 7)) * 8;
                fbh[jd] = *(const bf16v8*)&VH[rb][sb];
                fbl[jd] = *(const bf16v8*)&VL[rb][sb];
            }
#pragma unroll
            for (int iq = 0; iq < 2; ++iq)
#pragma unroll
                for (int jd = 0; jd < 2; ++jd) {
                    acco[iq][jd] = __builtin_amdgcn_mfma_f32_16x16x32_bf16(
                        pah[iq], fbh[jd], acco[iq][jd], 0, 0, 0);
                    acco[iq][jd] = __builtin_amdgcn_mfma_f32_16x16x32_bf16(
                        pah[iq], fbl[jd], acco[iq][jd], 0, 0, 0);
                    acco[iq][jd] = __builtin_amdgcn_mfma_f32_16x16x32_bf16(
                        pal[iq], fbh[jd], acco[iq][jd], 0, 0, 0);
                }
        }
    }

    // epilogue: o row-major [4096][1024], col = h*64 + d, bf16 hi/lo
#pragma unroll
    for (int jd = 0; jd < 2; ++jd) {
        const int dcol = wc * 32 + jd * 16 + fr;
#pragma unroll
        for (int iq = 0; iq < 2; ++iq) {
            const int row0 = i0 + wrp * 32 + iq * 16 + fq * 4;
            const f32v4 cv = acco[iq][jd];
#pragma unroll
            for (int r = 0; r < 4; ++r) {
                unsigned short hv, lv;
                split2(cv[r], hv, lv);
                const size_t idx = (size_t)(bq * 1024 + row0 + r) * 1024 + hd * 64 + dcol;
                oh[idx] = hv;
                ol[idx] = lv;
            }
        }
    }
}

// ---------------------------------------------------------------------------
extern "C" void kernel_launch(void* const* d_in, const int* in_sizes, int n_in,
                              void* d_out, int out_size, void* d_ws, size_t ws_size,
                              hipStream_t stream)
{
    const float* query = (const float*)d_in[0];
    const float* key_  = (const float*)d_in[1];
    const float* value = (const float*)d_in[2];
    const float* Wq  = (const float*)d_in[3];
    const float* bq  = (const float*)d_in[4];
    const float* Wk  = (const float*)d_in[5];
    const float* bk  = (const float*)d_in[6];
    const float* Wv  = (const float*)d_in[7];
    const float* bv  = (const float*)d_in[8];
    const float* Wp  = (const float*)d_in[9];
    const float* bp  = (const float*)d_in[10];
    const float* Wup = (const float*)d_in[11];
    const float* bup = (const float*)d_in[12];
    const float* Wud = (const float*)d_in[13];
    const float* bud = (const float*)d_in[14];
    const float* Wus = (const float*)d_in[15];
    const float* bus = (const float*)d_in[16];
    const float* Wo  = (const float*)d_in[17];
    const float* bo  = (const float*)d_in[18];

    float* x_out = (float*)d_out;                         // [4096,1024]
    float* attn  = x_out + (size_t)MTOT * HIDN;           // [64,1024,1024]

    // ---- workspace layout (bytes)
    char* wsb = (char*)d_ws;
    unsigned short* qh  = (unsigned short*)(wsb);                  // 8 MB
    unsigned short* ql  = (unsigned short*)(wsb + (8u  << 20));
    unsigned short* kh  = (unsigned short*)(wsb + (16u << 20));
    unsigned short* kl  = (unsigned short*)(wsb + (24u << 20));
    unsigned short* vTh = (unsigned short*)(wsb + (32u << 20));
    unsigned short* vTl = (unsigned short*)(wsb + (40u << 20));
    float* p_ws  = (float*)(wsb + (48u << 20));                    // 16 MB
    unsigned short* oh = (unsigned short*)(wsb + (48u << 20));     // overlays p
    unsigned short* ol = (unsigned short*)(wsb + (56u << 20));
    float* alpha_ws = (float*)(wsb + (64u << 20));                 // 256 KB
    float* cen_ws   = (float*)(wsb + (64u << 20) + (256u << 10));
    float* c0_ws    = (float*)(wsb + (64u << 20) + (512u << 10));
    // stage-1 split scratch lives in the (not-yet-written) attn region
    unsigned short* ah = (unsigned short*)attn;                    // 8 MB
    unsigned short* al = ah + (size_t)MTOT * HIDN;                 // 8 MB
    unsigned short* wh = al + (size_t)MTOT * HIDN;                 // 2 MB
    unsigned short* wl = wh + (size_t)HIDN * HIDN;                 // 2 MB
    // Wo split reuses qh/ql space after attn_fused
    unsigned short* w2h = qh;
    unsigned short* w2l = ql;

    const dim3 blk(256);
    const dim3 blk512(512);
    const dim3 gsplit_a(MTOT * HIDN / 8 / 256);
    const dim3 gsplit_w(16, 16);
    const dim3 ggemm(HIDN / 64, MTOT / 128);   // (16, 32) = 512 blocks

    // q = query @ Wq + bq -> qh/ql (bf16 only)
    split_w<<<gsplit_w, blk, 0, stream>>>(Wq, wh, wl);
    split_a<<<gsplit_a, blk, 0, stream>>>(query, ah, al);
    gemm_bf16x3<<<ggemm, blk512, 0, stream>>>(ah, al, wh, wl, bq, nullptr, qh, ql, 0);
    // k -> kh/kl
    split_w<<<gsplit_w, blk, 0, stream>>>(Wk, wh, wl);
    split_a<<<gsplit_a, blk, 0, stream>>>(key_, ah, al);
    gemm_bf16x3<<<ggemm, blk512, 0, stream>>>(ah, al, wh, wl, bk, nullptr, kh, kl, 0);
    // v -> vTh/vTl (per-head transposed)
    split_w<<<gsplit_w, blk, 0, stream>>>(Wv, wh, wl);
    split_a<<<gsplit_a, blk, 0, stream>>>(value, ah, al);
    gemm_bf16x3<<<ggemm, blk512, 0, stream>>>(ah, al, wh, wl, bv, nullptr, vTh, vTl, 1);
    // p = q @ Wp + bp -> p_ws (f32); A is already-split qh/ql
    split_w<<<gsplit_w, blk, 0, stream>>>(Wp, wh, wl);
    gemm_bf16x3<<<ggemm, blk512, 0, stream>>>(qh, ql, wh, wl, bp, p_ws, nullptr, nullptr, 0);
    // alpha + window params
    alpha_kernel<<<dim3(MTOT / 16), blk, 0, stream>>>(query, Wus, bus, alpha_ws);
    posparam_kernel<<<dim3((BATCH * NHEAD * S_LEN) / 256), blk, 0, stream>>>(
        p_ws, alpha_ws, Wup, bup, Wud, bud, cen_ws, c0_ws);
    // fused scores + softmax + attn-write + PV (512 blocks x 512 threads)
    attn_fused<<<dim3(512), blk512, 0, stream>>>(
        qh, ql, kh, kl, vTh, vTl, cen_ws, c0_ws, attn, oh, ol);
    // x = o @ Wo + bo
    split_w<<<gsplit_w, blk, 0, stream>>>(Wo, w2h, w2l);
    gemm_bf16x3<<<ggemm, blk512, 0, stream>>>(oh, ol, w2h, w2l, bo, x_out,
                                              nullptr, nullptr, 0);
}

// Round 8
// 390.373 us; speedup vs baseline: 1.2965x; 1.2965x over previous
//
#include <hip/hip_runtime.h>
#include <hip/hip_bf16.h>
#include <math.h>

#define S_LEN 1024
#define HIDN  1024
#define NHEAD 16
#define HDIM  64
#define BATCH 4
#define MTOT  (BATCH * S_LEN)   // 4096

typedef __attribute__((ext_vector_type(8))) short          bf16v8;
typedef __attribute__((ext_vector_type(8))) unsigned short u16v8;
typedef __attribute__((ext_vector_type(4))) unsigned short u16v4;
typedef __attribute__((ext_vector_type(4))) float          f32v4;

// ---------------------------------------------------------------------------
// bf16 hi/lo split helpers (RNE)
// ---------------------------------------------------------------------------
__device__ __forceinline__ unsigned short f2bf_rne(float x) {
    unsigned int u = __float_as_uint(x);
    unsigned int r = (u + 0x7fffu + ((u >> 16) & 1u)) >> 16;
    return (unsigned short)r;
}
__device__ __forceinline__ float bf2f(unsigned short h) {
    return __uint_as_float(((unsigned int)h) << 16);
}
__device__ __forceinline__ void split2(float x, unsigned short& h, unsigned short& l) {
    h = f2bf_rne(x);
    l = f2bf_rne(x - bf2f(h));
}

// ---------------------------------------------------------------------------
// split_a: row-major f32 [M][1024] -> Ah, Al bf16 (same layout).
// ---------------------------------------------------------------------------
__global__ __launch_bounds__(256) void split_a(
    const float* __restrict__ X, unsigned short* __restrict__ H,
    unsigned short* __restrict__ L)
{
    const int i = blockIdx.x * 256 + threadIdx.x;
    const float4 x0 = ((const float4*)X)[2 * i];
    const float4 x1 = ((const float4*)X)[2 * i + 1];
    float xs[8] = {x0.x, x0.y, x0.z, x0.w, x1.x, x1.y, x1.z, x1.w};
    u16v8 h, l;
#pragma unroll
    for (int j = 0; j < 8; ++j) {
        unsigned short hh, ll;
        split2(xs[j], hh, ll);
        h[j] = hh; l[j] = ll;
    }
    ((u16v8*)H)[i] = h;
    ((u16v8*)L)[i] = l;
}

// ---------------------------------------------------------------------------
// split_w: W f32 [K=1024][N=1024] -> transposed Ht, Lt bf16 [N][K] (k-contig).
// ---------------------------------------------------------------------------
__global__ __launch_bounds__(256) void split_w(
    const float* __restrict__ W, unsigned short* __restrict__ H,
    unsigned short* __restrict__ L)
{
    __shared__ float T[64][65];
    const int t  = threadIdx.x;
    const int k0 = blockIdx.y * 64;
    const int n0 = blockIdx.x * 64;

    const int r = t >> 4;
    const int c = (t & 15) * 4;
#pragma unroll
    for (int i = 0; i < 4; ++i) {
        const int rr = r + i * 16;
        const float4 v = *(const float4*)&W[(size_t)(k0 + rr) * 1024 + n0 + c];
        T[rr][c + 0] = v.x; T[rr][c + 1] = v.y;
        T[rr][c + 2] = v.z; T[rr][c + 3] = v.w;
    }
    __syncthreads();

    const int n  = t >> 2;
    const int ko = (t & 3) * 16;
    u16v8 h0, h1, l0, l1;
#pragma unroll
    for (int kk = 0; kk < 8; ++kk) {
        unsigned short hh, ll;
        split2(T[ko + kk][n], hh, ll);
        h0[kk] = hh; l0[kk] = ll;
    }
#pragma unroll
    for (int kk = 0; kk < 8; ++kk) {
        unsigned short hh, ll;
        split2(T[ko + 8 + kk][n], hh, ll);
        h1[kk] = hh; l1[kk] = ll;
    }
    unsigned short* Hp = &H[(size_t)(n0 + n) * 1024 + k0 + ko];
    unsigned short* Lp = &L[(size_t)(n0 + n) * 1024 + k0 + ko];
    *(u16v8*)(Hp)     = h0;
    *(u16v8*)(Hp + 8) = h1;
    *(u16v8*)(Lp)     = l0;
    *(u16v8*)(Lp + 8) = l1;
}

// ---------------------------------------------------------------------------
// bf16x3 MFMA GEMM: C = A(hi/lo bf16 [M][1024]) @ B(hi/lo [n][k]) + bias.
// BM=128, BN=64, BK=32, 512 threads (8 waves 4x2), wave 32x32 out.
// launch_bounds(512,2): VGPR cap 128 (no spill), 2 blocks/CU = 16 waves/CU.
// ---------------------------------------------------------------------------
__global__ __launch_bounds__(512, 2) void gemm_bf16x3(
    const unsigned short* __restrict__ Ah, const unsigned short* __restrict__ Al,
    const unsigned short* __restrict__ Bh, const unsigned short* __restrict__ Bl,
    const float* __restrict__ bias, float* __restrict__ Cf,
    unsigned short* __restrict__ Ch, unsigned short* __restrict__ Cl, int vt)
{
    __shared__ short Ash[128][40];
    __shared__ short Asl[128][40];
    __shared__ short Bsh[64][40];
    __shared__ short Bsl[64][40];

    const int t    = threadIdx.x;
    const int bm   = blockIdx.y * 128;
    const int bn   = blockIdx.x * 64;
    const int lane = t & 63;
    const int wid  = t >> 6;        // 0..7
    const int wr   = wid >> 1;      // 0..3 -> rows wr*32
    const int wc   = wid & 1;       // cols wc*32
    const int fr   = lane & 15;
    const int fq   = lane >> 4;
    const int ks   = fq * 8;

    f32v4 zero = {0.f, 0.f, 0.f, 0.f};
    f32v4 acc[2][2];
#pragma unroll
    for (int i = 0; i < 2; ++i)
#pragma unroll
        for (int j = 0; j < 2; ++j) acc[i][j] = zero;

    // staging roles: each thread 1 chunk of Ah + Al; half threads Bh, half Bl
    const int sra = t >> 2;          // 0..127
    const int sca = (t & 3) * 8;
    const int tb  = t & 255;
    const int srb = tb >> 2;         // 0..63
    const int scb = (tb & 3) * 8;
    const bool isBl = (t >= 256);
    const unsigned short* pAh = &Ah[(size_t)(bm + sra) * 1024 + sca];
    const unsigned short* pAl = &Al[(size_t)(bm + sra) * 1024 + sca];
    const unsigned short* pB  = isBl ? &Bl[(size_t)(bn + srb) * 1024 + scb]
                                     : &Bh[(size_t)(bn + srb) * 1024 + scb];

    u16v8 rah, ral, rb;
    auto LOAD = [&](int k0) {
        rah = *(const u16v8*)(pAh + k0);
        ral = *(const u16v8*)(pAl + k0);
        rb  = *(const u16v8*)(pB  + k0);
    };

    LOAD(0);
    for (int k0 = 0; k0 < 1024; k0 += 32) {
        __syncthreads();
        *(u16v8*)&Ash[sra][sca] = rah;
        *(u16v8*)&Asl[sra][sca] = ral;
        if (isBl) *(u16v8*)&Bsl[srb][scb] = rb;
        else      *(u16v8*)&Bsh[srb][scb] = rb;
        __syncthreads();

        if (k0 + 32 < 1024) LOAD(k0 + 32);

        bf16v8 fah[2], fal[2], fbh[2], fbl[2];
#pragma unroll
        for (int i = 0; i < 2; ++i) {
            fah[i] = *(const bf16v8*)&Ash[wr * 32 + i * 16 + fr][ks];
            fal[i] = *(const bf16v8*)&Asl[wr * 32 + i * 16 + fr][ks];
        }
#pragma unroll
        for (int j = 0; j < 2; ++j) {
            fbh[j] = *(const bf16v8*)&Bsh[wc * 32 + j * 16 + fr][ks];
            fbl[j] = *(const bf16v8*)&Bsl[wc * 32 + j * 16 + fr][ks];
        }
#pragma unroll
        for (int i = 0; i < 2; ++i)
#pragma unroll
            for (int j = 0; j < 2; ++j) {
                acc[i][j] = __builtin_amdgcn_mfma_f32_16x16x32_bf16(
                    fah[i], fbh[j], acc[i][j], 0, 0, 0);
                acc[i][j] = __builtin_amdgcn_mfma_f32_16x16x32_bf16(
                    fah[i], fbl[j], acc[i][j], 0, 0, 0);
                acc[i][j] = __builtin_amdgcn_mfma_f32_16x16x32_bf16(
                    fal[i], fbh[j], acc[i][j], 0, 0, 0);
            }
    }

#pragma unroll
    for (int j = 0; j < 2; ++j) {
        const int col = bn + wc * 32 + j * 16 + fr;
        const float bb = bias[col];
#pragma unroll
        for (int i = 0; i < 2; ++i) {
            const int row0 = bm + wr * 32 + i * 16 + fq * 4;
            const f32v4 cv = acc[i][j];
            if (vt) {
                u16v4 h4, l4;
#pragma unroll
                for (int r = 0; r < 4; ++r) {
                    unsigned short hh, ll;
                    split2(cv[r] + bb, hh, ll);
                    h4[r] = hh; l4[r] = ll;
                }
                const size_t base =
                    ((size_t)((row0 >> 10) * 16 + (col >> 6)) * 64 + (col & 63)) * 1024
                    + (row0 & 1023);
                *(u16v4*)&Ch[base] = h4;
                *(u16v4*)&Cl[base] = l4;
            } else {
#pragma unroll
                for (int r = 0; r < 4; ++r) {
                    const float v = cv[r] + bb;
                    const size_t idx = (size_t)(row0 + r) * 1024 + col;
                    if (Cf) Cf[idx] = v;
                    if (Ch) {
                        unsigned short hh, ll;
                        split2(v, hh, ll);
                        Ch[idx] = hh; Cl[idx] = ll;
                    }
                }
            }
        }
    }
}

// ---------------------------------------------------------------------------
// alpha = sigmoid(query @ Wus + bus)   [MTOT,16]
// ---------------------------------------------------------------------------
__global__ __launch_bounds__(256) void alpha_kernel(
    const float* __restrict__ X, const float* __restrict__ Wus,
    const float* __restrict__ bus, float* __restrict__ alpha)
{
    __shared__ float Ws[1024 * 16];
    const int t = threadIdx.x;
#pragma unroll
    for (int i = 0; i < 16; ++i) {
        const int idx = t + i * 256;
        *reinterpret_cast<float4*>(&Ws[idx * 4]) =
            *reinterpret_cast<const float4*>(&Wus[idx * 4]);
    }
    __syncthreads();

    const int r = t >> 4, c = t & 15;
    const size_t row = (size_t)blockIdx.x * 16 + r;
    const float* x = &X[row * 1024];
    float acc = 0.f;
    for (int kk = 0; kk < 1024; kk += 4) {
        const float4 xv = *reinterpret_cast<const float4*>(&x[kk]);
        acc = fmaf(xv.x, Ws[(kk + 0) * 16 + c], acc);
        acc = fmaf(xv.y, Ws[(kk + 1) * 16 + c], acc);
        acc = fmaf(xv.z, Ws[(kk + 2) * 16 + c], acc);
        acc = fmaf(xv.w, Ws[(kk + 3) * 16 + c], acc);
    }
    acc += bus[c];
    alpha[row * 16 + c] = 1.f / (1.f + expf(-acc));
}

// ---------------------------------------------------------------------------
// Gaussian-window parameters per (b,h,s)
// ---------------------------------------------------------------------------
__global__ __launch_bounds__(256) void posparam_kernel(
    const float* __restrict__ p, const float* __restrict__ alpha,
    const float* __restrict__ Wup, const float* __restrict__ bup,
    const float* __restrict__ Wud, const float* __restrict__ bud,
    float* __restrict__ cen, float* __restrict__ c0)
{
    __shared__ float wu[64], wd[64];
    const int t = threadIdx.x;
    if (t < 64) { wu[t] = Wup[t]; wd[t] = Wud[t]; }
    __syncthreads();

    const int tid = blockIdx.x * 256 + t;
    const int b = tid >> 14;
    const int h = (tid >> 10) & 15;
    const int s = tid & 1023;

    const float* pr = &p[((size_t)(b * 1024 + s)) * 1024 + h * 64];
    float ap = 0.f, az = 0.f;
#pragma unroll
    for (int d = 0; d < 64; d += 4) {
        const float4 pv = *reinterpret_cast<const float4*>(&pr[d]);
        const float t0 = tanhf(pv.x), t1 = tanhf(pv.y);
        const float t2 = tanhf(pv.z), t3 = tanhf(pv.w);
        ap += t0 * wu[d] + t1 * wu[d + 1] + t2 * wu[d + 2] + t3 * wu[d + 3];
        az += t0 * wd[d] + t1 * wd[d + 1] + t2 * wd[d + 2] + t3 * wd[d + 3];
    }
    ap += bup[0];
    az += bud[0];
    const float cenv = 1024.f / (1.f + expf(-ap));
    const float win  = 1024.f / (1.f + expf(-az));
    const float al   = alpha[(size_t)(b * 1024 + s) * 16 + h];
    const int oi = (b * 16 + h) * 1024 + s;
    cen[oi] = cenv;
    c0[oi]  = al * 2.f / (win * win);
}

// ---------------------------------------------------------------------------
// attn_fused v5: identical structure to v4 (i-tile 128, grid 512, 8 waves,
// register prefetch) but launch_bounds(512,2): VGPR cap 128 -> no scratch
// spill (v4's (512,4) capped at 64 VGPR and spilled ~280 MB to HBM).
// 2 blocks/CU x 8 waves = 16 waves/CU.
// ---------------------------------------------------------------------------
#define M0_SHIFT 8.0f
__global__ __launch_bounds__(512, 2) void attn_fused(
    const unsigned short* __restrict__ qh, const unsigned short* __restrict__ ql,
    const unsigned short* __restrict__ kh, const unsigned short* __restrict__ kl,
    const unsigned short* __restrict__ vTh, const unsigned short* __restrict__ vTl,
    const float* __restrict__ cen, const float* __restrict__ c0,
    float* __restrict__ attn,
    unsigned short* __restrict__ oh, unsigned short* __restrict__ ol)
{
    __shared__ unsigned short KH[64][64], KL[64][64];   // 16 KB
    __shared__ unsigned short VH[64][64], VL[64][64];   // 16 KB
    __shared__ unsigned short PH[128][64], PL[128][64]; // 32 KB
    __shared__ float CEN[128], C0S[128];
    __shared__ float LSUM[2][128];
    __shared__ float RINV[128];

    // XCD mapping: all 8 i-tiles of one z land on one XCD (bid&7 = XCD)
    const int bid   = blockIdx.x;
    const int z     = ((bid >> 6) << 3) | (bid & 7);
    const int itile = (bid >> 3) & 7;
    const int i0    = itile * 128;
    const int bq    = z >> 4;
    const int hd    = z & 15;

    const int t    = threadIdx.x;
    const int lane = t & 63;
    const int wid  = t >> 6;        // 0..7
    const int wrp  = wid >> 1;      // 0..3 -> q rows wrp*32
    const int wc   = wid & 1;       // j cols wc*32
    const int fr   = lane & 15, fq = lane >> 4;

    if (t < 128) {
        CEN[t] = cen[(size_t)z * 1024 + i0 + t];
        C0S[t] = c0[(size_t)z * 1024 + i0 + t];
    }

    // Q fragments in registers (A-frag: row = fr, k = kk*32 + fq*8)
    bf16v8 qfh_[2][2], qfl_[2][2];
#pragma unroll
    for (int i = 0; i < 2; ++i)
#pragma unroll
        for (int kk = 0; kk < 2; ++kk) {
            const size_t qa = (size_t)(bq * 1024 + i0 + wrp * 32 + i * 16 + fr) * 1024
                              + hd * 64 + kk * 32 + fq * 8;
            qfh_[i][kk] = *(const bf16v8*)&qh[qa];
            qfl_[i][kk] = *(const bf16v8*)&ql[qa];
        }

    float lsum[2][4];
#pragma unroll
    for (int i = 0; i < 2; ++i)
#pragma unroll
        for (int r = 0; r < 4; ++r) lsum[i][r] = 0.f;

    const f32v4 zero = {0.f, 0.f, 0.f, 0.f};

    // staging role: thread -> K/V row (t>>3, 0..63), 8-elem seg (t&7)
    const int srow = t >> 3;
    const int sseg = t & 7;
    const int ssl  = (sseg ^ (srow & 7)) * 8;
    const unsigned short* vhb = vTh + (size_t)z * 64 * 1024;
    const unsigned short* vlb = vTl + (size_t)z * 64 * 1024;

    u16v8 rkh, rkl, rvh, rvl;
    auto LOADK = [&](int j0) {
        const size_t ga = (size_t)(bq * 1024 + j0 + srow) * 1024 + hd * 64 + sseg * 8;
        rkh = *(const u16v8*)&kh[ga];
        rkl = *(const u16v8*)&kl[ga];
    };
    auto LOADV = [&](int j0) {
        const size_t va = (size_t)srow * 1024 + j0 + sseg * 8;
        rvh = *(const u16v8*)&vhb[va];
        rvl = *(const u16v8*)&vlb[va];
    };

    // ---------------- PASS A: row sums ----------------
    LOADK(0);
    for (int jt = 0; jt < 16; ++jt) {
        const int j0 = jt * 64;
        __syncthreads();            // prev tile's readers done (also CEN ready)
        *(u16v8*)&KH[srow][ssl] = rkh;
        *(u16v8*)&KL[srow][ssl] = rkl;
        __syncthreads();
        if (jt < 15) LOADK(j0 + 64);   // prefetch next tile under compute

        f32v4 acc[2][2];
#pragma unroll
        for (int i = 0; i < 2; ++i)
#pragma unroll
            for (int j2 = 0; j2 < 2; ++j2) acc[i][j2] = zero;

#pragma unroll
        for (int kk = 0; kk < 2; ++kk) {
            bf16v8 fbh[2], fbl[2];
#pragma unroll
            for (int j2 = 0; j2 < 2; ++j2) {
                const int rb = wc * 32 + j2 * 16 + fr;
                const int sb = ((kk * 4 + fq) ^ (rb & 7)) * 8;
                fbh[j2] = *(const bf16v8*)&KH[rb][sb];
                fbl[j2] = *(const bf16v8*)&KL[rb][sb];
            }
#pragma unroll
            for (int i = 0; i < 2; ++i)
#pragma unroll
                for (int j2 = 0; j2 < 2; ++j2) {
                    acc[i][j2] = __builtin_amdgcn_mfma_f32_16x16x32_bf16(
                        qfh_[i][kk], fbh[j2], acc[i][j2], 0, 0, 0);
                    acc[i][j2] = __builtin_amdgcn_mfma_f32_16x16x32_bf16(
                        qfh_[i][kk], fbl[j2], acc[i][j2], 0, 0, 0);
                    acc[i][j2] = __builtin_amdgcn_mfma_f32_16x16x32_bf16(
                        qfl_[i][kk], fbh[j2], acc[i][j2], 0, 0, 0);
                }
        }

#pragma unroll
        for (int i = 0; i < 2; ++i)
#pragma unroll
            for (int r = 0; r < 4; ++r) {
                const int row = wrp * 32 + i * 16 + fq * 4 + r;
                const float cv = CEN[row], cc = C0S[row];
                float al = 0.f;
#pragma unroll
                for (int j2 = 0; j2 < 2; ++j2) {
                    const int col = wc * 32 + j2 * 16 + fr;
                    const float dd = (float)(j0 + col) - cv;
                    const float s  = acc[i][j2][r] * 0.125f - cc * dd * dd;
                    al += __expf(s - M0_SHIFT);
                }
                lsum[i][r] += al;
            }
    }

    // reduce over fr lanes, combine wc halves via LDS
#pragma unroll
    for (int i = 0; i < 2; ++i)
#pragma unroll
        for (int r = 0; r < 4; ++r) {
            float v = lsum[i][r];
            v += __shfl_xor(v, 1);
            v += __shfl_xor(v, 2);
            v += __shfl_xor(v, 4);
            v += __shfl_xor(v, 8);
            if (fr == 0) LSUM[wc][wrp * 32 + i * 16 + fq * 4 + r] = v;
        }
    __syncthreads();
    if (t < 128) RINV[t] = 1.f / (LSUM[0][t] + LSUM[1][t]);

    // ---------------- PASS B: attn write + PV ----------------
    f32v4 acco[2][2];
#pragma unroll
    for (int i = 0; i < 2; ++i)
#pragma unroll
        for (int j = 0; j < 2; ++j) acco[i][j] = zero;

    float* attnZ = attn + (size_t)z * 1024 * 1024;

    LOADK(0);
    LOADV(0);
    for (int jt = 0; jt < 16; ++jt) {
        const int j0 = jt * 64;
        __syncthreads();   // prev PV reads done; RINV visible on first iter
        *(u16v8*)&KH[srow][ssl] = rkh;
        *(u16v8*)&KL[srow][ssl] = rkl;
        *(u16v8*)&VH[srow][ssl] = rvh;
        *(u16v8*)&VL[srow][ssl] = rvl;
        __syncthreads();
        if (jt < 15) { LOADK(j0 + 64); LOADV(j0 + 64); }

        f32v4 acc[2][2];
#pragma unroll
        for (int i = 0; i < 2; ++i)
#pragma unroll
            for (int j2 = 0; j2 < 2; ++j2) acc[i][j2] = zero;

#pragma unroll
        for (int kk = 0; kk < 2; ++kk) {
            bf16v8 fbh[2], fbl[2];
#pragma unroll
            for (int j2 = 0; j2 < 2; ++j2) {
                const int rb = wc * 32 + j2 * 16 + fr;
                const int sb = ((kk * 4 + fq) ^ (rb & 7)) * 8;
                fbh[j2] = *(const bf16v8*)&KH[rb][sb];
                fbl[j2] = *(const bf16v8*)&KL[rb][sb];
            }
#pragma unroll
            for (int i = 0; i < 2; ++i)
#pragma unroll
                for (int j2 = 0; j2 < 2; ++j2) {
                    acc[i][j2] = __builtin_amdgcn_mfma_f32_16x16x32_bf16(
                        qfh_[i][kk], fbh[j2], acc[i][j2], 0, 0, 0);
                    acc[i][j2] = __builtin_amdgcn_mfma_f32_16x16x32_bf16(
                        qfh_[i][kk], fbl[j2], acc[i][j2], 0, 0, 0);
                    acc[i][j2] = __builtin_amdgcn_mfma_f32_16x16x32_bf16(
                        qfl_[i][kk], fbh[j2], acc[i][j2], 0, 0, 0);
                }
        }

        // P = exp(s-8)*rinv: write attn f32 + scatter bf16 hi/lo to LDS
#pragma unroll
        for (int i = 0; i < 2; ++i)
#pragma unroll
            for (int r = 0; r < 4; ++r) {
                const int row = wrp * 32 + i * 16 + fq * 4 + r;
                const float cv = CEN[row], cc = C0S[row], ri = RINV[row];
#pragma unroll
                for (int j2 = 0; j2 < 2; ++j2) {
                    const int col = wc * 32 + j2 * 16 + fr;
                    const float dd = (float)(j0 + col) - cv;
                    const float s  = acc[i][j2][r] * 0.125f - cc * dd * dd;
                    const float p  = __expf(s - M0_SHIFT) * ri;
                    attnZ[(size_t)(i0 + row) * 1024 + j0 + col] = p;
                    unsigned short hv, lv;
                    split2(p, hv, lv);
                    const int slot = ((col >> 3) ^ (row & 7)) * 8 + (col & 7);
                    PH[row][slot] = hv;
                    PL[row][slot] = lv;
                }
            }
        __syncthreads();

        // PV MFMA: out[128 q][64 d] += P[128][64] @ Vt[64 d][64 j]^T
#pragma unroll
        for (int kk = 0; kk < 2; ++kk) {
            bf16v8 pah[2], pal[2], fbh[2], fbl[2];
#pragma unroll
            for (int iq = 0; iq < 2; ++iq) {
                const int rp = wrp * 32 + iq * 16 + fr;
                const int sp = ((kk * 4 + fq) ^ (rp & 7)) * 8;
                pah[iq] = *(const bf16v8*)&PH[rp][sp];
                pal[iq] = *(const bf16v8*)&PL[rp][sp];
            }
#pragma unroll
            for (int jd = 0; jd < 2; ++jd) {
                const int rb = wc * 32 + jd * 16 + fr;
                const int sb = ((kk * 4 + fq) ^ (rb & 7)) * 8;
                fbh[jd] = *(const bf16v8*)&VH[rb][sb];
                fbl[jd] = *(const bf16v8*)&VL[rb][sb];
            }
#pragma unroll
            for (int iq = 0; iq < 2; ++iq)
#pragma unroll
                for (int jd = 0; jd < 2; ++jd) {
                    acco[iq][jd] = __builtin_amdgcn_mfma_f32_16x16x32_bf16(
                        pah[iq], fbh[jd], acco[iq][jd], 0, 0, 0);
                    acco[iq][jd] = __builtin_amdgcn_mfma_f32_16x16x32_bf16(
                        pah[iq], fbl[jd], acco[iq][jd], 0, 0, 0);
                    acco[iq][jd] = __builtin_amdgcn_mfma_f32_16x16x32_bf16(
                        pal[iq], fbh[jd], acco[iq][jd], 0, 0, 0);
                }
        }
    }

    // epilogue: o row-major [4096][1024], col = h*64 + d, bf16 hi/lo
#pragma unroll
    for (int jd = 0; jd < 2; ++jd) {
        const int dcol = wc * 32 + jd * 16 + fr;
#pragma unroll
        for (int iq = 0; iq < 2; ++iq) {
            const int row0 = i0 + wrp * 32 + iq * 16 + fq * 4;
            const f32v4 cv = acco[iq][jd];
#pragma unroll
            for (int r = 0; r < 4; ++r) {
                unsigned short hv, lv;
                split2(cv[r], hv, lv);
                const size_t idx = (size_t)(bq * 1024 + row0 + r) * 1024 + hd * 64 + dcol;
                oh[idx] = hv;
                ol[idx] = lv;
            }
        }
    }
}

// ---------------------------------------------------------------------------
extern "C" void kernel_launch(void* const* d_in, const int* in_sizes, int n_in,
                              void* d_out, int out_size, void* d_ws, size_t ws_size,
                              hipStream_t stream)
{
    const float* query = (const float*)d_in[0];
    const float* key_  = (const float*)d_in[1];
    const float* value = (const float*)d_in[2];
    const float* Wq  = (const float*)d_in[3];
    const float* bq  = (const float*)d_in[4];
    const float* Wk  = (const float*)d_in[5];
    const float* bk  = (const float*)d_in[6];
    const float* Wv  = (const float*)d_in[7];
    const float* bv  = (const float*)d_in[8];
    const float* Wp  = (const float*)d_in[9];
    const float* bp  = (const float*)d_in[10];
    const float* Wup = (const float*)d_in[11];
    const float* bup = (const float*)d_in[12];
    const float* Wud = (const float*)d_in[13];
    const float* bud = (const float*)d_in[14];
    const float* Wus = (const float*)d_in[15];
    const float* bus = (const float*)d_in[16];
    const float* Wo  = (const float*)d_in[17];
    const float* bo  = (const float*)d_in[18];

    float* x_out = (float*)d_out;                         // [4096,1024]
    float* attn  = x_out + (size_t)MTOT * HIDN;           // [64,1024,1024]

    // ---- workspace layout (bytes)
    char* wsb = (char*)d_ws;
    unsigned short* qh  = (unsigned short*)(wsb);                  // 8 MB
    unsigned short* ql  = (unsigned short*)(wsb + (8u  << 20));
    unsigned short* kh  = (unsigned short*)(wsb + (16u << 20));
    unsigned short* kl  = (unsigned short*)(wsb + (24u << 20));
    unsigned short* vTh = (unsigned short*)(wsb + (32u << 20));
    unsigned short* vTl = (unsigned short*)(wsb + (40u << 20));
    float* p_ws  = (float*)(wsb + (48u << 20));                    // 16 MB
    unsigned short* oh = (unsigned short*)(wsb + (48u << 20));     // overlays p
    unsigned short* ol = (unsigned short*)(wsb + (56u << 20));
    float* alpha_ws = (float*)(wsb + (64u << 20));                 // 256 KB
    float* cen_ws   = (float*)(wsb + (64u << 20) + (256u << 10));
    float* c0_ws    = (float*)(wsb + (64u << 20) + (512u << 10));
    // stage-1 split scratch lives in the (not-yet-written) attn region
    unsigned short* ah = (unsigned short*)attn;                    // 8 MB
    unsigned short* al = ah + (size_t)MTOT * HIDN;                 // 8 MB
    unsigned short* wh = al + (size_t)MTOT * HIDN;                 // 2 MB
    unsigned short* wl = wh + (size_t)HIDN * HIDN;                 // 2 MB
    // Wo split reuses qh/ql space after attn_fused
    unsigned short* w2h = qh;
    unsigned short* w2l = ql;

    const dim3 blk(256);
    const dim3 blk512(512);
    const dim3 gsplit_a(MTOT * HIDN / 8 / 256);
    const dim3 gsplit_w(16, 16);
    const dim3 ggemm(HIDN / 64, MTOT / 128);   // (16, 32) = 512 blocks

    // q = query @ Wq + bq -> qh/ql (bf16 only)
    split_w<<<gsplit_w, blk, 0, stream>>>(Wq, wh, wl);
    split_a<<<gsplit_a, blk, 0, stream>>>(query, ah, al);
    gemm_bf16x3<<<ggemm, blk512, 0, stream>>>(ah, al, wh, wl, bq, nullptr, qh, ql, 0);
    // k -> kh/kl
    split_w<<<gsplit_w, blk, 0, stream>>>(Wk, wh, wl);
    split_a<<<gsplit_a, blk, 0, stream>>>(key_, ah, al);
    gemm_bf16x3<<<ggemm, blk512, 0, stream>>>(ah, al, wh, wl, bk, nullptr, kh, kl, 0);
    // v -> vTh/vTl (per-head transposed)
    split_w<<<gsplit_w, blk, 0, stream>>>(Wv, wh, wl);
    split_a<<<gsplit_a, blk, 0, stream>>>(value, ah, al);
    gemm_bf16x3<<<ggemm, blk512, 0, stream>>>(ah, al, wh, wl, bv, nullptr, vTh, vTl, 1);
    // p = q @ Wp + bp -> p_ws (f32); A is already-split qh/ql
    split_w<<<gsplit_w, blk, 0, stream>>>(Wp, wh, wl);
    gemm_bf16x3<<<ggemm, blk512, 0, stream>>>(qh, ql, wh, wl, bp, p_ws, nullptr, nullptr, 0);
    // alpha + window params
    alpha_kernel<<<dim3(MTOT / 16), blk, 0, stream>>>(query, Wus, bus, alpha_ws);
    posparam_kernel<<<dim3((BATCH * NHEAD * S_LEN) / 256), blk, 0, stream>>>(
        p_ws, alpha_ws, Wup, bup, Wud, bud, cen_ws, c0_ws);
    // fused scores + softmax + attn-write + PV (512 blocks x 512 threads)
    attn_fused<<<dim3(512), blk512, 0, stream>>>(
        qh, ql, kh, kl, vTh, vTl, cen_ws, c0_ws, attn, oh, ol);
    // x = o @ Wo + bo
    split_w<<<gsplit_w, blk, 0, stream>>>(Wo, w2h, w2l);
    gemm_bf16x3<<<ggemm, blk512, 0, stream>>>(oh, ol, w2h, w2l, bo, x_out,
                                              nullptr, nullptr, 0);
}

// Round 9
// 379.931 us; speedup vs baseline: 1.3321x; 1.0275x over previous
//
#include <hip/hip_runtime.h>
#include <hip/hip_bf16.h>
#include <math.h>

#define S_LEN 1024
#define HIDN  1024
#define NHEAD 16
#define HDIM  64
#define BATCH 4
#define MTOT  (BATCH * S_LEN)   // 4096

typedef __attribute__((ext_vector_type(8))) short          bf16v8;
typedef __attribute__((ext_vector_type(8))) unsigned short u16v8;
typedef __attribute__((ext_vector_type(4))) unsigned short u16v4;
typedef __attribute__((ext_vector_type(4))) float          f32v4;

// ---------------------------------------------------------------------------
// bf16 hi/lo split helpers (RNE)
// ---------------------------------------------------------------------------
__device__ __forceinline__ unsigned short f2bf_rne(float x) {
    unsigned int u = __float_as_uint(x);
    unsigned int r = (u + 0x7fffu + ((u >> 16) & 1u)) >> 16;
    return (unsigned short)r;
}
__device__ __forceinline__ float bf2f(unsigned short h) {
    return __uint_as_float(((unsigned int)h) << 16);
}
__device__ __forceinline__ void split2(float x, unsigned short& h, unsigned short& l) {
    h = f2bf_rne(x);
    l = f2bf_rne(x - bf2f(h));
}

// ---------------------------------------------------------------------------
// split_w4: z-batched weight split. W f32 [K][N] -> transposed hi/lo [N][K].
// dest slot z at Hbase/Lbase + z*1M elems.
// ---------------------------------------------------------------------------
__global__ __launch_bounds__(256) void split_w4(
    const float* __restrict__ W0, const float* __restrict__ W1,
    const float* __restrict__ W2, const float* __restrict__ W3,
    unsigned short* __restrict__ Hbase, unsigned short* __restrict__ Lbase)
{
    __shared__ float T[64][65];
    const int t  = threadIdx.x;
    const int k0 = blockIdx.y * 64;
    const int n0 = blockIdx.x * 64;
    const int z  = blockIdx.z;
    const float* W = (z == 0) ? W0 : (z == 1) ? W1 : (z == 2) ? W2 : W3;
    unsigned short* H = Hbase + (size_t)z * 1024 * 1024;
    unsigned short* L = Lbase + (size_t)z * 1024 * 1024;

    const int r = t >> 4;
    const int c = (t & 15) * 4;
#pragma unroll
    for (int i = 0; i < 4; ++i) {
        const int rr = r + i * 16;
        const float4 v = *(const float4*)&W[(size_t)(k0 + rr) * 1024 + n0 + c];
        T[rr][c + 0] = v.x; T[rr][c + 1] = v.y;
        T[rr][c + 2] = v.z; T[rr][c + 3] = v.w;
    }
    __syncthreads();

    const int n  = t >> 2;
    const int ko = (t & 3) * 16;
    u16v8 h0, h1, l0, l1;
#pragma unroll
    for (int kk = 0; kk < 8; ++kk) {
        unsigned short hh, ll;
        split2(T[ko + kk][n], hh, ll);
        h0[kk] = hh; l0[kk] = ll;
    }
#pragma unroll
    for (int kk = 0; kk < 8; ++kk) {
        unsigned short hh, ll;
        split2(T[ko + 8 + kk][n], hh, ll);
        h1[kk] = hh; l1[kk] = ll;
    }
    unsigned short* Hp = &H[(size_t)(n0 + n) * 1024 + k0 + ko];
    unsigned short* Lp = &L[(size_t)(n0 + n) * 1024 + k0 + ko];
    *(u16v8*)(Hp)     = h0;
    *(u16v8*)(Hp + 8) = h1;
    *(u16v8*)(Lp)     = l0;
    *(u16v8*)(Lp + 8) = l1;
}

// ---------------------------------------------------------------------------
// Templated bf16x3 MFMA GEMM. BM=128, BN=64, BK=32, 512 threads (8 waves 4x2),
// wave 32x32 out, launch_bounds(512,2) -> 128 VGPR cap, no spill.
// AF32: 1 = A is raw f32 (split inline during staging), 0 = pre-split bf16.
// EPI:  0 = f32 out (+bias), 1 = bf16 hi/lo out, 2 = per-head-transposed
//       bf16 out (for V), 3 = fused posparam (p never materialized).
// ---------------------------------------------------------------------------
template<int AF32, int EPI>
__global__ __launch_bounds__(512, 2) void gemm_t(
    const float* __restrict__ Af,
    const unsigned short* __restrict__ Ah, const unsigned short* __restrict__ Al,
    const unsigned short* __restrict__ Bh, const unsigned short* __restrict__ Bl,
    const float* __restrict__ bias, float* __restrict__ Cf,
    unsigned short* __restrict__ Ch, unsigned short* __restrict__ Cl,
    const float* __restrict__ Wup, const float* __restrict__ Wud,
    const float* __restrict__ bup, const float* __restrict__ bud,
    const float* __restrict__ alpha, float* __restrict__ cenp,
    float* __restrict__ c0p)
{
    __shared__ short Ash[128][40];
    __shared__ short Asl[128][40];
    __shared__ short Bsh[64][40];
    __shared__ short Bsl[64][40];
    __shared__ float PSUP[2][128], PSUD[2][128];   // posparam partials

    const int t    = threadIdx.x;
    const int bm   = blockIdx.y * 128;
    const int bn   = blockIdx.x * 64;
    const int lane = t & 63;
    const int wid  = t >> 6;        // 0..7
    const int wr   = wid >> 1;      // 0..3 -> rows wr*32
    const int wc   = wid & 1;       // cols wc*32
    const int fr   = lane & 15;
    const int fq   = lane >> 4;
    const int ks   = fq * 8;

    f32v4 zero = {0.f, 0.f, 0.f, 0.f};
    f32v4 acc[2][2];
#pragma unroll
    for (int i = 0; i < 2; ++i)
#pragma unroll
        for (int j = 0; j < 2; ++j) acc[i][j] = zero;

    // staging roles
    const int sra = t >> 2;          // 0..127
    const int sca = (t & 3) * 8;
    const int tb  = t & 255;
    const int srb = tb >> 2;         // 0..63
    const int scb = (tb & 3) * 8;
    const bool isBl = (t >= 256);
    const unsigned short* pB = isBl ? &Bl[(size_t)(bn + srb) * 1024 + scb]
                                    : &Bh[(size_t)(bn + srb) * 1024 + scb];
    const float* pAf = AF32 ? &Af[(size_t)(bm + sra) * 1024 + sca] : nullptr;
    const unsigned short* pAh = AF32 ? nullptr : &Ah[(size_t)(bm + sra) * 1024 + sca];
    const unsigned short* pAl = AF32 ? nullptr : &Al[(size_t)(bm + sra) * 1024 + sca];

    u16v8 rah, ral, rb;
    auto LOAD = [&](int k0) {
        if (AF32) {
            const float4 a0 = *(const float4*)(pAf + k0);
            const float4 a1 = *(const float4*)(pAf + k0 + 4);
            const float xs[8] = {a0.x, a0.y, a0.z, a0.w, a1.x, a1.y, a1.z, a1.w};
#pragma unroll
            for (int e = 0; e < 8; ++e) {
                unsigned short hh, ll;
                split2(xs[e], hh, ll);
                rah[e] = hh; ral[e] = ll;
            }
        } else {
            rah = *(const u16v8*)(pAh + k0);
            ral = *(const u16v8*)(pAl + k0);
        }
        rb = *(const u16v8*)(pB + k0);
    };

    LOAD(0);
    for (int k0 = 0; k0 < 1024; k0 += 32) {
        __syncthreads();
        *(u16v8*)&Ash[sra][sca] = rah;
        *(u16v8*)&Asl[sra][sca] = ral;
        if (isBl) *(u16v8*)&Bsl[srb][scb] = rb;
        else      *(u16v8*)&Bsh[srb][scb] = rb;
        __syncthreads();

        if (k0 + 32 < 1024) LOAD(k0 + 32);

        bf16v8 fah[2], fal[2], fbh[2], fbl[2];
#pragma unroll
        for (int i = 0; i < 2; ++i) {
            fah[i] = *(const bf16v8*)&Ash[wr * 32 + i * 16 + fr][ks];
            fal[i] = *(const bf16v8*)&Asl[wr * 32 + i * 16 + fr][ks];
        }
#pragma unroll
        for (int j = 0; j < 2; ++j) {
            fbh[j] = *(const bf16v8*)&Bsh[wc * 32 + j * 16 + fr][ks];
            fbl[j] = *(const bf16v8*)&Bsl[wc * 32 + j * 16 + fr][ks];
        }
#pragma unroll
        for (int i = 0; i < 2; ++i)
#pragma unroll
            for (int j = 0; j < 2; ++j) {
                acc[i][j] = __builtin_amdgcn_mfma_f32_16x16x32_bf16(
                    fah[i], fbh[j], acc[i][j], 0, 0, 0);
                acc[i][j] = __builtin_amdgcn_mfma_f32_16x16x32_bf16(
                    fah[i], fbl[j], acc[i][j], 0, 0, 0);
                acc[i][j] = __builtin_amdgcn_mfma_f32_16x16x32_bf16(
                    fal[i], fbh[j], acc[i][j], 0, 0, 0);
            }
    }

    if (EPI == 3) {
        // fused Gaussian-window params: tanh(p) dots with Wup/Wud, then
        // cen = S*sigmoid(.), c0 = alpha*2/win^2. p never written.
        float wupj[2], wudj[2];
        float bb[2];
#pragma unroll
        for (int j = 0; j < 2; ++j) {
            const int colL = wc * 32 + j * 16 + fr;
            wupj[j] = Wup[colL];
            wudj[j] = Wud[colL];
            bb[j]   = bias[bn + colL];
        }
        float su[2][4], sd[2][4];
#pragma unroll
        for (int i = 0; i < 2; ++i)
#pragma unroll
            for (int r = 0; r < 4; ++r) { su[i][r] = 0.f; sd[i][r] = 0.f; }
#pragma unroll
        for (int j = 0; j < 2; ++j)
#pragma unroll
            for (int i = 0; i < 2; ++i)
#pragma unroll
                for (int r = 0; r < 4; ++r) {
                    const float tv = tanhf(acc[i][j][r] + bb[j]);
                    su[i][r] = fmaf(tv, wupj[j], su[i][r]);
                    sd[i][r] = fmaf(tv, wudj[j], sd[i][r]);
                }
#pragma unroll
        for (int i = 0; i < 2; ++i)
#pragma unroll
            for (int r = 0; r < 4; ++r) {
                float a = su[i][r], d = sd[i][r];
                a += __shfl_xor(a, 1); d += __shfl_xor(d, 1);
                a += __shfl_xor(a, 2); d += __shfl_xor(d, 2);
                a += __shfl_xor(a, 4); d += __shfl_xor(d, 4);
                a += __shfl_xor(a, 8); d += __shfl_xor(d, 8);
                if (fr == 0) {
                    const int row = wr * 32 + i * 16 + fq * 4 + r;
                    PSUP[wc][row] = a;
                    PSUD[wc][row] = d;
                }
            }
        __syncthreads();
        if (t < 128) {
            const float ap = PSUP[0][t] + PSUP[1][t] + bup[0];
            const float az = PSUD[0][t] + PSUD[1][t] + bud[0];
            const float cenv = 1024.f / (1.f + expf(-ap));
            const float win  = 1024.f / (1.f + expf(-az));
            const int grow = bm + t;
            const int hd   = bn >> 6;
            const int zz   = (grow >> 10) * 16 + hd;
            const int s    = grow & 1023;
            const float al = alpha[(size_t)grow * 16 + hd];
            cenp[(size_t)zz * 1024 + s] = cenv;
            c0p[(size_t)zz * 1024 + s]  = al * 2.f / (win * win);
        }
        return;
    }

#pragma unroll
    for (int j = 0; j < 2; ++j) {
        const int col = bn + wc * 32 + j * 16 + fr;
        const float bb = bias[col];
#pragma unroll
        for (int i = 0; i < 2; ++i) {
            const int row0 = bm + wr * 32 + i * 16 + fq * 4;
            const f32v4 cv = acc[i][j];
            if (EPI == 2) {
                u16v4 h4, l4;
#pragma unroll
                for (int r = 0; r < 4; ++r) {
                    unsigned short hh, ll;
                    split2(cv[r] + bb, hh, ll);
                    h4[r] = hh; l4[r] = ll;
                }
                const size_t base =
                    ((size_t)((row0 >> 10) * 16 + (col >> 6)) * 64 + (col & 63)) * 1024
                    + (row0 & 1023);
                *(u16v4*)&Ch[base] = h4;
                *(u16v4*)&Cl[base] = l4;
            } else if (EPI == 1) {
#pragma unroll
                for (int r = 0; r < 4; ++r) {
                    unsigned short hh, ll;
                    split2(cv[r] + bb, hh, ll);
                    const size_t idx = (size_t)(row0 + r) * 1024 + col;
                    Ch[idx] = hh; Cl[idx] = ll;
                }
            } else {
#pragma unroll
                for (int r = 0; r < 4; ++r)
                    Cf[(size_t)(row0 + r) * 1024 + col] = cv[r] + bb;
            }
        }
    }
}

// ---------------------------------------------------------------------------
// alpha = sigmoid(query @ Wus + bus)   [MTOT,16]
// ---------------------------------------------------------------------------
__global__ __launch_bounds__(256) void alpha_kernel(
    const float* __restrict__ X, const float* __restrict__ Wus,
    const float* __restrict__ bus, float* __restrict__ alpha)
{
    __shared__ float Ws[1024 * 16];
    const int t = threadIdx.x;
#pragma unroll
    for (int i = 0; i < 16; ++i) {
        const int idx = t + i * 256;
        *reinterpret_cast<float4*>(&Ws[idx * 4]) =
            *reinterpret_cast<const float4*>(&Wus[idx * 4]);
    }
    __syncthreads();

    const int r = t >> 4, c = t & 15;
    const size_t row = (size_t)blockIdx.x * 16 + r;
    const float* x = &X[row * 1024];
    float acc = 0.f;
    for (int kk = 0; kk < 1024; kk += 4) {
        const float4 xv = *reinterpret_cast<const float4*>(&x[kk]);
        acc = fmaf(xv.x, Ws[(kk + 0) * 16 + c], acc);
        acc = fmaf(xv.y, Ws[(kk + 1) * 16 + c], acc);
        acc = fmaf(xv.z, Ws[(kk + 2) * 16 + c], acc);
        acc = fmaf(xv.w, Ws[(kk + 3) * 16 + c], acc);
    }
    acc += bus[c];
    alpha[row * 16 + c] = 1.f / (1.f + expf(-acc));
}

// ---------------------------------------------------------------------------
// attn_fused (unchanged from round 8, proven): i-tile 128, grid 512, 8 waves,
// register prefetch, launch_bounds(512,2).
// ---------------------------------------------------------------------------
#define M0_SHIFT 8.0f
__global__ __launch_bounds__(512, 2) void attn_fused(
    const unsigned short* __restrict__ qh, const unsigned short* __restrict__ ql,
    const unsigned short* __restrict__ kh, const unsigned short* __restrict__ kl,
    const unsigned short* __restrict__ vTh, const unsigned short* __restrict__ vTl,
    const float* __restrict__ cen, const float* __restrict__ c0,
    float* __restrict__ attn,
    unsigned short* __restrict__ oh, unsigned short* __restrict__ ol)
{
    __shared__ unsigned short KH[64][64], KL[64][64];   // 16 KB
    __shared__ unsigned short VH[64][64], VL[64][64];   // 16 KB
    __shared__ unsigned short PH[128][64], PL[128][64]; // 32 KB
    __shared__ float CEN[128], C0S[128];
    __shared__ float LSUM[2][128];
    __shared__ float RINV[128];

    const int bid   = blockIdx.x;
    const int z     = ((bid >> 6) << 3) | (bid & 7);
    const int itile = (bid >> 3) & 7;
    const int i0    = itile * 128;
    const int bq    = z >> 4;
    const int hd    = z & 15;

    const int t    = threadIdx.x;
    const int lane = t & 63;
    const int wid  = t >> 6;
    const int wrp  = wid >> 1;
    const int wc   = wid & 1;
    const int fr   = lane & 15, fq = lane >> 4;

    if (t < 128) {
        CEN[t] = cen[(size_t)z * 1024 + i0 + t];
        C0S[t] = c0[(size_t)z * 1024 + i0 + t];
    }

    bf16v8 qfh_[2][2], qfl_[2][2];
#pragma unroll
    for (int i = 0; i < 2; ++i)
#pragma unroll
        for (int kk = 0; kk < 2; ++kk) {
            const size_t qa = (size_t)(bq * 1024 + i0 + wrp * 32 + i * 16 + fr) * 1024
                              + hd * 64 + kk * 32 + fq * 8;
            qfh_[i][kk] = *(const bf16v8*)&qh[qa];
            qfl_[i][kk] = *(const bf16v8*)&ql[qa];
        }

    float lsum[2][4];
#pragma unroll
    for (int i = 0; i < 2; ++i)
#pragma unroll
        for (int r = 0; r < 4; ++r) lsum[i][r] = 0.f;

    const f32v4 zero = {0.f, 0.f, 0.f, 0.f};

    const int srow = t >> 3;
    const int sseg = t & 7;
    const int ssl  = (sseg ^ (srow & 7)) * 8;
    const unsigned short* vhb = vTh + (size_t)z * 64 * 1024;
    const unsigned short* vlb = vTl + (size_t)z * 64 * 1024;

    u16v8 rkh, rkl, rvh, rvl;
    auto LOADK = [&](int j0) {
        const size_t ga = (size_t)(bq * 1024 + j0 + srow) * 1024 + hd * 64 + sseg * 8;
        rkh = *(const u16v8*)&kh[ga];
        rkl = *(const u16v8*)&kl[ga];
    };
    auto LOADV = [&](int j0) {
        const size_t va = (size_t)srow * 1024 + j0 + sseg * 8;
        rvh = *(const u16v8*)&vhb[va];
        rvl = *(const u16v8*)&vlb[va];
    };

    // ---------------- PASS A ----------------
    LOADK(0);
    for (int jt = 0; jt < 16; ++jt) {
        const int j0 = jt * 64;
        __syncthreads();
        *(u16v8*)&KH[srow][ssl] = rkh;
        *(u16v8*)&KL[srow][ssl] = rkl;
        __syncthreads();
        if (jt < 15) LOADK(j0 + 64);

        f32v4 acc[2][2];
#pragma unroll
        for (int i = 0; i < 2; ++i)
#pragma unroll
            for (int j2 = 0; j2 < 2; ++j2) acc[i][j2] = zero;

#pragma unroll
        for (int kk = 0; kk < 2; ++kk) {
            bf16v8 fbh[2], fbl[2];
#pragma unroll
            for (int j2 = 0; j2 < 2; ++j2) {
                const int rb = wc * 32 + j2 * 16 + fr;
                const int sb = ((kk * 4 + fq) ^ (rb & 7)) * 8;
                fbh[j2] = *(const bf16v8*)&KH[rb][sb];
                fbl[j2] = *(const bf16v8*)&KL[rb][sb];
            }
#pragma unroll
            for (int i = 0; i < 2; ++i)
#pragma unroll
                for (int j2 = 0; j2 < 2; ++j2) {
                    acc[i][j2] = __builtin_amdgcn_mfma_f32_16x16x32_bf16(
                        qfh_[i][kk], fbh[j2], acc[i][j2], 0, 0, 0);
                    acc[i][j2] = __builtin_amdgcn_mfma_f32_16x16x32_bf16(
                        qfh_[i][kk], fbl[j2], acc[i][j2], 0, 0, 0);
                    acc[i][j2] = __builtin_amdgcn_mfma_f32_16x16x32_bf16(
                        qfl_[i][kk], fbh[j2], acc[i][j2], 0, 0, 0);
                }
        }

#pragma unroll
        for (int i = 0; i < 2; ++i)
#pragma unroll
            for (int r = 0; r < 4; ++r) {
                const int row = wrp * 32 + i * 16 + fq * 4 + r;
                const float cv = CEN[row], cc = C0S[row];
                float al = 0.f;
#pragma unroll
                for (int j2 = 0; j2 < 2; ++j2) {
                    const int col = wc * 32 + j2 * 16 + fr;
                    const float dd = (float)(j0 + col) - cv;
                    const float s  = acc[i][j2][r] * 0.125f - cc * dd * dd;
                    al += __expf(s - M0_SHIFT);
                }
                lsum[i][r] += al;
            }
    }

#pragma unroll
    for (int i = 0; i < 2; ++i)
#pragma unroll
        for (int r = 0; r < 4; ++r) {
            float v = lsum[i][r];
            v += __shfl_xor(v, 1);
            v += __shfl_xor(v, 2);
            v += __shfl_xor(v, 4);
            v += __shfl_xor(v, 8);
            if (fr == 0) LSUM[wc][wrp * 32 + i * 16 + fq * 4 + r] = v;
        }
    __syncthreads();
    if (t < 128) RINV[t] = 1.f / (LSUM[0][t] + LSUM[1][t]);

    // ---------------- PASS B ----------------
    f32v4 acco[2][2];
#pragma unroll
    for (int i = 0; i < 2; ++i)
#pragma unroll
        for (int j = 0; j < 2; ++j) acco[i][j] = zero;

    float* attnZ = attn + (size_t)z * 1024 * 1024;

    LOADK(0);
    LOADV(0);
    for (int jt = 0; jt < 16; ++jt) {
        const int j0 = jt * 64;
        __syncthreads();
        *(u16v8*)&KH[srow][ssl] = rkh;
        *(u16v8*)&KL[srow][ssl] = rkl;
        *(u16v8*)&VH[srow][ssl] = rvh;
        *(u16v8*)&VL[srow][ssl] = rvl;
        __syncthreads();
        if (jt < 15) { LOADK(j0 + 64); LOADV(j0 + 64); }

        f32v4 acc[2][2];
#pragma unroll
        for (int i = 0; i < 2; ++i)
#pragma unroll
            for (int j2 = 0; j2 < 2; ++j2) acc[i][j2] = zero;

#pragma unroll
        for (int kk = 0; kk < 2; ++kk) {
            bf16v8 fbh[2], fbl[2];
#pragma unroll
            for (int j2 = 0; j2 < 2; ++j2) {
                const int rb = wc * 32 + j2 * 16 + fr;
                const int sb = ((kk * 4 + fq) ^ (rb & 7)) * 8;
                fbh[j2] = *(const bf16v8*)&KH[rb][sb];
                fbl[j2] = *(const bf16v8*)&KL[rb][sb];
            }
#pragma unroll
            for (int i = 0; i < 2; ++i)
#pragma unroll
                for (int j2 = 0; j2 < 2; ++j2) {
                    acc[i][j2] = __builtin_amdgcn_mfma_f32_16x16x32_bf16(
                        qfh_[i][kk], fbh[j2], acc[i][j2], 0, 0, 0);
                    acc[i][j2] = __builtin_amdgcn_mfma_f32_16x16x32_bf16(
                        qfh_[i][kk], fbl[j2], acc[i][j2], 0, 0, 0);
                    acc[i][j2] = __builtin_amdgcn_mfma_f32_16x16x32_bf16(
                        qfl_[i][kk], fbh[j2], acc[i][j2], 0, 0, 0);
                }
        }

#pragma unroll
        for (int i = 0; i < 2; ++i)
#pragma unroll
            for (int r = 0; r < 4; ++r) {
                const int row = wrp * 32 + i * 16 + fq * 4 + r;
                const float cv = CEN[row], cc = C0S[row], ri = RINV[row];
#pragma unroll
                for (int j2 = 0; j2 < 2; ++j2) {
                    const int col = wc * 32 + j2 * 16 + fr;
                    const float dd = (float)(j0 + col) - cv;
                    const float s  = acc[i][j2][r] * 0.125f - cc * dd * dd;
                    const float p  = __expf(s - M0_SHIFT) * ri;
                    attnZ[(size_t)(i0 + row) * 1024 + j0 + col] = p;
                    unsigned short hv, lv;
                    split2(p, hv, lv);
                    const int slot = ((col >> 3) ^ (row & 7)) * 8 + (col & 7);
                    PH[row][slot] = hv;
                    PL[row][slot] = lv;
                }
            }
        __syncthreads();

#pragma unroll
        for (int kk = 0; kk < 2; ++kk) {
            bf16v8 pah[2], pal[2], fbh[2], fbl[2];
#pragma unroll
            for (int iq = 0; iq < 2; ++iq) {
                const int rp = wrp * 32 + iq * 16 + fr;
                const int sp = ((kk * 4 + fq) ^ (rp & 7)) * 8;
                pah[iq] = *(const bf16v8*)&PH[rp][sp];
                pal[iq] = *(const bf16v8*)&PL[rp][sp];
            }
#pragma unroll
            for (int jd = 0; jd < 2; ++jd) {
                const int rb = wc * 32 + jd * 16 + fr;
                const int sb = ((kk * 4 + fq) ^ (rb & 7)) * 8;
                fbh[jd] = *(const bf16v8*)&VH[rb][sb];
                fbl[jd] = *(const bf16v8*)&VL[rb][sb];
            }
#pragma unroll
            for (int iq = 0; iq < 2; ++iq)
#pragma unroll
                for (int jd = 0; jd < 2; ++jd) {
                    acco[iq][jd] = __builtin_amdgcn_mfma_f32_16x16x32_bf16(
                        pah[iq], fbh[jd], acco[iq][jd], 0, 0, 0);
                    acco[iq][jd] = __builtin_amdgcn_mfma_f32_16x16x32_bf16(
                        pah[iq], fbl[jd], acco[iq][jd], 0, 0, 0);
                    acco[iq][jd] = __builtin_amdgcn_mfma_f32_16x16x32_bf16(
                        pal[iq], fbh[jd], acco[iq][jd], 0, 0, 0);
                }
        }
    }

#pragma unroll
    for (int jd = 0; jd < 2; ++jd) {
        const int dcol = wc * 32 + jd * 16 + fr;
#pragma unroll
        for (int iq = 0; iq < 2; ++iq) {
            const int row0 = i0 + wrp * 32 + iq * 16 + fq * 4;
            const f32v4 cv = acco[iq][jd];
#pragma unroll
            for (int r = 0; r < 4; ++r) {
                unsigned short hv, lv;
                split2(cv[r], hv, lv);
                const size_t idx = (size_t)(bq * 1024 + row0 + r) * 1024 + hd * 64 + dcol;
                oh[idx] = hv;
                ol[idx] = lv;
            }
        }
    }
}

// ---------------------------------------------------------------------------
extern "C" void kernel_launch(void* const* d_in, const int* in_sizes, int n_in,
                              void* d_out, int out_size, void* d_ws, size_t ws_size,
                              hipStream_t stream)
{
    const float* query = (const float*)d_in[0];
    const float* key_  = (const float*)d_in[1];
    const float* value = (const float*)d_in[2];
    const float* Wq  = (const float*)d_in[3];
    const float* bq  = (const float*)d_in[4];
    const float* Wk  = (const float*)d_in[5];
    const float* bk  = (const float*)d_in[6];
    const float* Wv  = (const float*)d_in[7];
    const float* bv  = (const float*)d_in[8];
    const float* Wp  = (const float*)d_in[9];
    const float* bp  = (const float*)d_in[10];
    const float* Wup = (const float*)d_in[11];
    const float* bup = (const float*)d_in[12];
    const float* Wud = (const float*)d_in[13];
    const float* bud = (const float*)d_in[14];
    const float* Wus = (const float*)d_in[15];
    const float* bus = (const float*)d_in[16];
    const float* Wo  = (const float*)d_in[17];
    const float* bo  = (const float*)d_in[18];

    float* x_out = (float*)d_out;                         // [4096,1024]
    float* attn  = x_out + (size_t)MTOT * HIDN;           // [64,1024,1024]

    // ---- workspace layout (bytes)
    char* wsb = (char*)d_ws;
    unsigned short* qh  = (unsigned short*)(wsb);                  // 8 MB
    unsigned short* ql  = (unsigned short*)(wsb + (8u  << 20));
    unsigned short* kh  = (unsigned short*)(wsb + (16u << 20));
    unsigned short* kl  = (unsigned short*)(wsb + (24u << 20));
    unsigned short* vTh = (unsigned short*)(wsb + (32u << 20));
    unsigned short* vTl = (unsigned short*)(wsb + (40u << 20));
    unsigned short* oh  = (unsigned short*)(wsb + (48u << 20));    // 8 MB
    unsigned short* ol  = (unsigned short*)(wsb + (56u << 20));
    float* alpha_ws = (float*)(wsb + (64u << 20));                 // 256 KB
    float* cen_ws   = (float*)(wsb + (64u << 20) + (256u << 10));
    float* c0_ws    = (float*)(wsb + (64u << 20) + (512u << 10));
    // weight splits for Wq/Wk/Wv/Wp live in the (not-yet-written) attn region
    unsigned short* wh = (unsigned short*)attn;                    // 4 x 2 MB
    unsigned short* wl = wh + (size_t)4 * 1024 * 1024;             // 4 x 2 MB
    // Wo split reuses qh/ql space after attn_fused
    unsigned short* w2h = qh;
    unsigned short* w2l = ql;

    const dim3 blk(256);
    const dim3 blk512(512);
    const dim3 ggemm(HIDN / 64, MTOT / 128);   // (16, 32) = 512 blocks
    const size_t WSTEP = (size_t)1024 * 1024;

    // weight splits (Wq,Wk,Wv,Wp) batched
    split_w4<<<dim3(16, 16, 4), blk, 0, stream>>>(Wq, Wk, Wv, Wp, wh, wl);
    // alpha (needed by fused posparam)
    alpha_kernel<<<dim3(MTOT / 16), blk, 0, stream>>>(query, Wus, bus, alpha_ws);
    // q = query @ Wq + bq -> qh/ql (inline f32-A split)
    gemm_t<1, 1><<<ggemm, blk512, 0, stream>>>(
        query, nullptr, nullptr, wh, wl, bq, nullptr, qh, ql,
        nullptr, nullptr, nullptr, nullptr, nullptr, nullptr, nullptr);
    // k -> kh/kl
    gemm_t<1, 1><<<ggemm, blk512, 0, stream>>>(
        key_, nullptr, nullptr, wh + WSTEP, wl + WSTEP, bk, nullptr, kh, kl,
        nullptr, nullptr, nullptr, nullptr, nullptr, nullptr, nullptr);
    // v -> vTh/vTl (per-head transposed)
    gemm_t<1, 2><<<ggemm, blk512, 0, stream>>>(
        value, nullptr, nullptr, wh + 2 * WSTEP, wl + 2 * WSTEP, bv,
        nullptr, vTh, vTl,
        nullptr, nullptr, nullptr, nullptr, nullptr, nullptr, nullptr);
    // p = q @ Wp + bp with fused posparam -> cen/c0 (p never materialized)
    gemm_t<0, 3><<<ggemm, blk512, 0, stream>>>(
        nullptr, qh, ql, wh + 3 * WSTEP, wl + 3 * WSTEP, bp, nullptr,
        nullptr, nullptr,
        Wup, Wud, bup, bud, alpha_ws, cen_ws, c0_ws);
    // fused scores + softmax + attn-write + PV
    attn_fused<<<dim3(512), blk512, 0, stream>>>(
        qh, ql, kh, kl, vTh, vTl, cen_ws, c0_ws, attn, oh, ol);
    // Wo split (into dead qh/ql region), then x = o @ Wo + bo
    split_w4<<<dim3(16, 16, 1), blk, 0, stream>>>(Wo, Wo, Wo, Wo, w2h, w2l);
    gemm_t<0, 0><<<ggemm, blk512, 0, stream>>>(
        nullptr, oh, ol, w2h, w2l, bo, x_out, nullptr, nullptr,
        nullptr, nullptr, nullptr, nullptr, nullptr, nullptr, nullptr);
}